// Round 1
// baseline (297.685 us; speedup 1.0000x reference)
//
#include <hip/hip_runtime.h>
#include <math.h>

// Fused LSTM, bf16 MFMA, BQ=4 on 256 CUs, replicated-row MFMA (round 9).
// B=1024,T=256,D=128,H=64,G=256,O=128. 256 blocks x 256 thr (4 waves).
// Block owns 4 batches. Wave w owns gate cols {64q+16w+lq}.
//
// Key change vs round 8: recurrent-MFMA A rows are relabeled m = 4*b + rr
// with the SAME h[b] fragment in all 4 rr slots (address depends only on
// b=(lane&15)>>2 and qd -> free 4-way LDS broadcast). The D tile
// (col=lane&15, row=4*(lane>>4)+reg) then delivers the FULL gate value for
// cell (b=qd, j=16w+lq) replicated in every reg of lane (qd,lq): the gbw
// LDS round-trip (store+lgkmcnt+load ~250 cy on the serial chain) is GONE,
// and C-init {gx,0,0,0} folds the gx add into the MFMA.
// Same relabel in the gx burst (x staged as m = 4*b + ts'): burst output
// lands directly in gxr registers -> gxw (32 KB) + its round-trip deleted.
// hfrag pitch 72->96 shorts: fragment read is exactly 2-way (free) instead
// of (lq+qd)-collided ~8-way (was the 8.4M SQ_LDS_BANK_CONFLICT).
// Per-step serial chain is now: barrier -> 2 ds_read_b128 (broadcast) ->
// 8 MFMA -> activations -> 1 ds_write_b16 -> barrier. One LDS round trip
// per step (minimum for the cross-wave h exchange).
constexpr int B = 1024, T = 256, D = 128, H = 64, O = 128;
constexpr int BQ = 4;
constexpr int NBLK = B / BQ;   // 256 blocks
constexpr int TC = 8;          // timesteps per chunk
constexpr int NCH = T / TC;    // 32 chunks

typedef __attribute__((ext_vector_type(8))) short short8;
typedef __attribute__((ext_vector_type(4))) float f32x4;

__device__ __forceinline__ unsigned short f2bf(float f) {
    union { float f; unsigned u; } v; v.f = f;
    return (unsigned short)((v.u + 0x7FFF + ((v.u >> 16) & 1)) >> 16);  // RNE
}
__device__ __forceinline__ float frcp(float x) { return __builtin_amdgcn_rcpf(x); }
__device__ __forceinline__ float sigmoidf_(float x) {
    return frcp(1.0f + __expf(-x));
}
__device__ __forceinline__ float tanhf_(float x) {
    return fmaf(2.0f, frcp(1.0f + __expf(-2.0f * x)), -1.0f);  // overflow-safe
}
// LDS-visibility barrier that does NOT drain outstanding global loads.
__device__ __forceinline__ void lds_barrier() {
    asm volatile("s_waitcnt lgkmcnt(0)\n\ts_barrier" ::: "memory");
}

__global__ __launch_bounds__(256, 1)
void lstm_fused(const float* __restrict__ x, const float* __restrict__ Wih,
                const float* __restrict__ Whh, const float* __restrict__ bih,
                const float* __restrict__ bhh, const float* __restrict__ Wo,
                const float* __restrict__ bo, float* __restrict__ out)
{
    // xfrag: [g][c][64 fraglanes][8] bf16 per ts-group g (rows m = 4*b+ts'),
    // XOR-swizzled: byte off in g-slab = c*1024 + ((fraglane*16) ^ (c*32)).
    __shared__ unsigned short xfrag[2 * 2048];   // 8 KB
    // hfrag: [buf][4 batch rows][96] bf16 (pitch 96 shorts -> 2-way reads)
    __shared__ unsigned short hfrag[2 * 4 * 96]; // 1.5 KB
    __shared__ float hfin[4 * 64];               // final h fp32      1 KB

    const int tid  = threadIdx.x;
    const int lane = tid & 63;
    const int w    = tid >> 6;
    const int lq   = lane & 15;
    const int qd   = lane >> 4;
    const int b0   = blockIdx.x * BQ;

    // ---- weight B-fragments (constant over t; verified R2-R7 layout) ----
    short8 wih_f[4][4];
    short8 whh_f[4][2];
    float  bias[4];
    #pragma unroll
    for (int q = 0; q < 4; ++q) {
        const int n = 64 * q + 16 * w + lq;
        #pragma unroll
        for (int c = 0; c < 4; ++c) {
            const float* p = Wih + (size_t)n * D + 32 * c + 8 * qd;
            short8 v;
            #pragma unroll
            for (int j = 0; j < 8; ++j) v[j] = (short)f2bf(p[j]);
            wih_f[q][c] = v;
        }
        #pragma unroll
        for (int c = 0; c < 2; ++c) {
            const float* p = Whh + (size_t)n * H + 32 * c + 8 * qd;
            short8 v;
            #pragma unroll
            for (int j = 0; j < 8; ++j) v[j] = (short)f2bf(p[j]);
            whh_f[q][c] = v;
        }
        bias[q] = bih[n] + bhh[n];
    }

    // ---- staging geometry: thread stages row m=ms of each g-slab ----
    // m = 4*b + ts'  ->  b = ms>>2, ts' = ms&3   (row relabel vs round 8!)
    const int ms    = tid >> 4;
    const int kslot = tid & 15;
    const int c_p   = kslot >> 2;
    const int q_p   = kslot & 3;
    const int l_p   = (q_p << 4) | ms;
    const int xoff  = c_p * 1024 + ((l_p * 16) ^ (c_p * 32));  // bytes in g-slab
    const int bb    = ms >> 2, tsp = ms & 3;
    const float* xbase = x + (size_t)(b0 + bb) * T * D + 8 * kslot;

    int xro[4];
    #pragma unroll
    for (int c = 0; c < 4; ++c) xro[c] = c * 1024 + ((lane * 16) ^ (c * 32));

    // ---- zero hfrag (h0 = 0); 768 shorts = 384 dwords ----
    for (int i = tid; i < 384; i += 256) ((unsigned int*)hfrag)[i] = 0;

    float4 pf[2][2];   // in-flight x loads for one chunk (2 g-groups)

    // prologue: xfrag=ch0 -> gx(ch0) -> xfrag=ch1, pf=ch2
    #pragma unroll
    for (int g = 0; g < 2; ++g) {
        const float* p = xbase + (size_t)(4 * g + tsp) * D;
        pf[g][0] = *(const float4*)p;
        pf[g][1] = *(const float4*)(p + 4);
    }
    #pragma unroll
    for (int g = 0; g < 2; ++g) {
        float4 a = pf[g][0], bv = pf[g][1];
        short8 v;
        v[0] = (short)f2bf(a.x);  v[1] = (short)f2bf(a.y);
        v[2] = (short)f2bf(a.z);  v[3] = (short)f2bf(a.w);
        v[4] = (short)f2bf(bv.x); v[5] = (short)f2bf(bv.y);
        v[6] = (short)f2bf(bv.z); v[7] = (short)f2bf(bv.w);
        *(short8*)((char*)xfrag + g * 4096 + xoff) = v;
    }
    #pragma unroll
    for (int g = 0; g < 2; ++g) {
        const float* p = xbase + (size_t)(TC + 4 * g + tsp) * D;
        pf[g][0] = *(const float4*)p;
        pf[g][1] = *(const float4*)(p + 4);
    }
    __syncthreads();

    float gxr[TC][4];   // gx in cell layout, 32 f32 regs

    // gx burst: ts-packed x-MFMAs, output lands DIRECTLY in gxr.
    // D rows = 4*b + ts' -> lane (qd,lq) reg r = gx(b=qd, t0+r, col 16w+lq)
    // for gate-tile q. No LDS round trip, no barrier needed for gx itself.
    auto gx_burst = [&]() {
        #pragma unroll
        for (int g = 0; g < 2; ++g) {
            short8 xf[4];
            #pragma unroll
            for (int c = 0; c < 4; ++c)
                xf[c] = *(const short8*)((char*)xfrag + g * 4096 + xro[c]);
            #pragma unroll
            for (int q = 0; q < 4; ++q) {
                f32x4 a = {bias[q], bias[q], bias[q], bias[q]};
                #pragma unroll
                for (int c = 0; c < 4; ++c)
                    a = __builtin_amdgcn_mfma_f32_16x16x32_bf16(xf[c], wih_f[q][c], a, 0, 0, 0);
                #pragma unroll
                for (int r = 0; r < 4; ++r) gxr[4 * g + r][q] = a[r];
            }
        }
    };

    gx_burst();        // chunk 0
    lds_barrier();     // all waves done reading xfrag(ch0)
    #pragma unroll
    for (int g = 0; g < 2; ++g) {          // commit ch1
        float4 a = pf[g][0], bv = pf[g][1];
        short8 v;
        v[0] = (short)f2bf(a.x);  v[1] = (short)f2bf(a.y);
        v[2] = (short)f2bf(a.z);  v[3] = (short)f2bf(a.w);
        v[4] = (short)f2bf(bv.x); v[5] = (short)f2bf(bv.y);
        v[6] = (short)f2bf(bv.z); v[7] = (short)f2bf(bv.w);
        *(short8*)((char*)xfrag + g * 4096 + xoff) = v;
    }
    #pragma unroll
    for (int g = 0; g < 2; ++g) {          // issue ch2
        const float* p = xbase + (size_t)(2 * TC + 4 * g + tsp) * D;
        pf[g][0] = *(const float4*)p;
        pf[g][1] = *(const float4*)(p + 4);
    }

    float cst = 0.0f, hlast = 0.0f;

    for (int ch = 0; ch < NCH; ++ch) {
        #pragma unroll
        for (int tt = 0; tt < TC; ++tt) {
            const int hcur = tt & 1, hnxt = hcur ^ 1;

            // A-fragment: row m = 4*b + rr holds h[b][32c+8qd..+7] for ALL
            // rr (address is rr-independent -> 4-way broadcast, 2-way banks)
            short8 hfr[2];
            #pragma unroll
            for (int c = 0; c < 2; ++c)
                hfr[c] = *(const short8*)(hfrag + hcur * 384 +
                                          (lq >> 2) * 96 + 32 * c + 8 * qd);

            // D row 4*qd+reg = 4*b+rr with b=qd: every reg of lane (qd,lq)
            // holds the FULL gate for cell (b=qd, j=16w+lq); C-init folds gx.
            float gv[4];
            #pragma unroll
            for (int q = 0; q < 4; ++q) {
                f32x4 a = {gxr[tt][q], 0.0f, 0.0f, 0.0f};
                #pragma unroll
                for (int c = 0; c < 2; ++c)
                    a = __builtin_amdgcn_mfma_f32_16x16x32_bf16(hfr[c], whh_f[q][c], a, 0, 0, 0);
                gv[q] = a[0];
            }

            float gi = sigmoidf_(gv[0]);
            float gf = sigmoidf_(gv[1]);
            float gg = tanhf_  (gv[2]);
            float go = sigmoidf_(gv[3]);
            float c2 = fmaf(gf, cst, gi * gg);
            cst = c2;
            float hv = go * tanhf_(c2);
            hlast = hv;
            hfrag[hnxt * 384 + qd * 96 + 16 * w + lq] = f2bf(hv);

            lds_barrier();   // h(t+1) visible to all waves
        }

        if (ch + 1 < NCH) {
            gx_burst();      // gx(ch+1) from xfrag (holds x(ch+1))
            lds_barrier();   // everyone done reading xfrag
            #pragma unroll
            for (int g = 0; g < 2; ++g) {      // commit x(ch+2)
                float4 a = pf[g][0], bv = pf[g][1];
                short8 v;
                v[0] = (short)f2bf(a.x);  v[1] = (short)f2bf(a.y);
                v[2] = (short)f2bf(a.z);  v[3] = (short)f2bf(a.w);
                v[4] = (short)f2bf(bv.x); v[5] = (short)f2bf(bv.y);
                v[6] = (short)f2bf(bv.z); v[7] = (short)f2bf(bv.w);
                *(short8*)((char*)xfrag + g * 4096 + xoff) = v;
            }
            const int ch3 = (ch + 3 < NCH) ? ch + 3 : NCH - 1;
            #pragma unroll
            for (int g = 0; g < 2; ++g) {      // issue x(ch+3)
                const float* p = xbase + ((size_t)ch3 * TC + 4 * g + tsp) * D;
                pf[g][0] = *(const float4*)p;
                pf[g][1] = *(const float4*)(p + 4);
            }
            // no barrier: 8 inner barriers of next chunk separate these
            // writes from the next boundary's reads
        }
    }

    // ---- epilogue: logits = relu(h) Wo^T + bo ; log_softmax over O=128 ----
    hfin[qd * 64 + 16 * w + lq] = hlast;
    __syncthreads();

    {
        const int m = w;                       // wave w handles batch w
        float l0 = bo[lane], l1 = bo[lane + 64];
        const float* w0 = Wo + (size_t)lane * H;
        const float* w1 = Wo + (size_t)(lane + 64) * H;
        #pragma unroll
        for (int k = 0; k < H; ++k) {
            float rh = fmaxf(hfin[m * 64 + k], 0.0f);
            l0 += rh * w0[k];
            l1 += rh * w1[k];
        }
        float mx = fmaxf(l0, l1);
        #pragma unroll
        for (int sh = 32; sh > 0; sh >>= 1) mx = fmaxf(mx, __shfl_xor(mx, sh));
        float e = __expf(l0 - mx) + __expf(l1 - mx);
        #pragma unroll
        for (int sh = 32; sh > 0; sh >>= 1) e += __shfl_xor(e, sh);
        float lse = mx + __logf(e);
        float* op = out + (size_t)(b0 + m) * O;
        op[lane]      = l0 - lse;
        op[lane + 64] = l1 - lse;
    }
}

extern "C" void kernel_launch(void* const* d_in, const int* in_sizes, int n_in,
                              void* d_out, int out_size, void* d_ws, size_t ws_size,
                              hipStream_t stream) {
    const float* x   = (const float*)d_in[0];
    const float* Wih = (const float*)d_in[1];
    const float* Whh = (const float*)d_in[2];
    const float* bih = (const float*)d_in[3];
    const float* bhh = (const float*)d_in[4];
    const float* Wo  = (const float*)d_in[5];
    const float* bo  = (const float*)d_in[6];
    lstm_fused<<<dim3(NBLK), dim3(256), 0, stream>>>(
        x, Wih, Whh, bih, bhh, Wo, bo, (float*)d_out);
}